// Round 13
// baseline (221.091 us; speedup 1.0000x reference)
//
#include <hip/hip_runtime.h>
#include <stdint.h>

#define B_  4
#define T_  2048
#define C_  1024
#define NH_ 16
#define HD_ 64
#define BH_ (B_*NH_)   // 64
#define M_  (B_*T_)    // 8192

using f32x4  = __attribute__((ext_vector_type(4))) float;
using f32x16 = __attribute__((ext_vector_type(16))) float;
using bf16x8 = __attribute__((ext_vector_type(8))) short;   // 8 bf16 in 4 VGPRs

__device__ __forceinline__ unsigned short f2bf(float x) {
  union { float f; uint32_t u; } v; v.f = x;
  uint32_t u = v.u;
  return (unsigned short)((u + 0x7FFFu + ((u >> 16) & 1u)) >> 16);  // RNE
}

__device__ __forceinline__ uint32_t cvtpk(float a, float b) {
  uint32_t r;
  asm("v_cvt_pk_bf16_f32 %0, %1, %2" : "=v"(r) : "v"(a), "v"(b));
  return r;
}

// async global->LDS, 16B per lane. lds ptr must be wave-uniform base; HW adds lane*16.
__device__ __forceinline__ void gload16(const void* g, void* l) {
  __builtin_amdgcn_global_load_lds(
      (const __attribute__((address_space(1))) void*)g,
      (__attribute__((address_space(3))) void*)l, 16, 0, 0);
}

#define BAR() do { asm volatile("" ::: "memory"); __builtin_amdgcn_s_barrier(); \
                   asm volatile("" ::: "memory"); } while (0)
#define VMC(N) asm volatile("s_waitcnt vmcnt(" #N ")" ::: "memory")

// ---------------- prep kernels ----------------

__global__ void k_cvt_bf16(const float* __restrict__ src,
                           unsigned short* __restrict__ dst, int n) {
  int i = (blockIdx.x * 256 + threadIdx.x) * 4;
  if (i + 3 < n) {
    float4 v = *(const float4*)(src + i);
    ushort4 o;
    o.x = f2bf(v.x); o.y = f2bf(v.y); o.z = f2bf(v.z); o.w = f2bf(v.w);
    *(ushort4*)(dst + i) = o;
  }
}

// W [K][N] f32 -> WT [N][K] bf16, 32x32 LDS tile
__global__ void k_transpose_w(const float* __restrict__ W,
                              unsigned short* __restrict__ WT, int K, int N) {
  __shared__ float tile[32][33];
  int bx = blockIdx.x, by = blockIdx.y;
  int tx = threadIdx.x, ty = threadIdx.y;   // (32,8)
  #pragma unroll
  for (int i = 0; i < 32; i += 8)
    tile[ty + i][tx] = W[(size_t)(by*32 + ty + i) * N + bx*32 + tx];
  __syncthreads();
  #pragma unroll
  for (int i = 0; i < 32; i += 8)
    WT[(size_t)(bx*32 + ty + i) * K + by*32 + tx] = f2bf(tile[tx][ty + i]);
}

__global__ void k_rope_tab(float* __restrict__ cosT, float* __restrict__ sinT) {
  int t = blockIdx.x * 8 + threadIdx.y;   // block (32,8)
  int i = threadIdx.x;                    // 0..31
  float inv = expf(-(float)i * (9.210340371976184f / 32.0f));
  float f = (float)t * inv;
  cosT[t*32 + i] = cosf(f);
  sinT[t*32 + i] = sinf(f);
}

// ---- GEMM: 128x128 tile, BK=32, 4 waves, 4-buffer ring, prefetch depth 3 ----
// R12 diagnosis: MfmaUtil pinned ~21% across all depth-1 variants => per-K-step
// vmcnt wait (~500-900cy L3/HBM latency vs ~300cy body) is the floor. Depth-3
// ring (STG t+3, VMC(12): 3 tiles always in flight) covers ~750cy. 64KB LDS
// keeps R8's proven 2 blocks/CU. Swizzle FIX vs R12: slot s of row r holds
// granule s ^ f(r), f(r) = (r&3)^((r>>2)&3) -> 2-way max (free), not 4-way.
// A: [M][K] bf16 row-major. BT: [N][K] bf16 (B^T, K-contiguous).
template<int N, int K, int EPI>
__global__ __launch_bounds__(256, 2)
void k_gemm(const unsigned short* __restrict__ Ag,
            const unsigned short* __restrict__ BT,
            const float* __restrict__ bias,
            const float* __restrict__ cosT,
            const float* __restrict__ sinT,
            unsigned short* __restrict__ Qh,
            unsigned short* __restrict__ Kh,
            unsigned short* __restrict__ VhT,
            float* __restrict__ outF) {
  __shared__ alignas(16) unsigned short As[4][128*32];   // 8 KB x4
  __shared__ alignas(16) unsigned short Bs[4][128*32];   // 8 KB x4 => 64 KB total
  const int tid  = threadIdx.x;
  const int lane = tid & 63;
  const int wv   = tid >> 6;
  const int wm   = wv >> 1, wn = wv & 1;
  const int l15  = lane & 15, l4 = lane >> 4;
  // XCD-aware bijective swizzle (grid % 8 == 0), n-fastest within chunk.
  const int NT  = N / 128;
  const int id  = ((int)blockIdx.x & 7) * ((int)gridDim.x >> 3) + ((int)blockIdx.x >> 3);
  const int m0  = (id / NT) * 128;
  const int n0  = (id % NT) * 128;

  f32x4 acc[4][4] = {};

  // ---- hoisted LDS read pointers; slot s = l4 ^ f(row), f mi/wm-invariant ----
  const int fr = (l15 & 3) ^ ((l15 >> 2) & 3);
  const int sA = l4 ^ fr;
  const unsigned short* aP0 = &As[0][(wm*64 + l15)*32 + sA*8];   // + mi*512 imm
  const unsigned short* aP1 = &As[1][(wm*64 + l15)*32 + sA*8];
  const unsigned short* aP2 = &As[2][(wm*64 + l15)*32 + sA*8];
  const unsigned short* aP3 = &As[3][(wm*64 + l15)*32 + sA*8];
  const unsigned short* bP0 = &Bs[0][(wn*64 + l15)*32 + sA*8];   // + ni*512 imm
  const unsigned short* bP1 = &Bs[1][(wn*64 + l15)*32 + sA*8];
  const unsigned short* bP2 = &Bs[2][(wn*64 + l15)*32 + sA*8];
  const unsigned short* bP3 = &Bs[3][(wn*64 + l15)*32 + sA*8];

  // ---- hoisted staging offsets (64 rows x 4 slots per chunk, 256 threads) ----
  const int srow = tid >> 2;                                   // 0..63
  const int sg   = (tid & 3) ^ (srow & 3) ^ ((srow >> 2) & 3); // granule = slot^f(row)
  const int voff = srow*K + sg*8;                              // invariant to chunk+64
  const int ldsD = wv*512;                                     // wave's dest in chunk
  const unsigned short* Abase = Ag + (size_t)m0*K;
  const unsigned short* Bbase = BT + (size_t)n0*K;

#define STG(BUF, KT) do { \
  const int _u = (KT)*32; \
  gload16(Abase + (0*64*K + _u) + voff, (void*)(&As[BUF][0*2048 + ldsD])); \
  gload16(Abase + (1*64*K + _u) + voff, (void*)(&As[BUF][1*2048 + ldsD])); \
  gload16(Bbase + (0*64*K + _u) + voff, (void*)(&Bs[BUF][0*2048 + ldsD])); \
  gload16(Bbase + (1*64*K + _u) + voff, (void*)(&Bs[BUF][1*2048 + ldsD])); \
} while (0)

#define CMP(AR, BR) do { \
  bf16x8 afr[4], bfr[4]; \
  _Pragma("unroll") for (int mi = 0; mi < 4; ++mi) \
    afr[mi] = *(const bf16x8*)((AR) + mi*512); \
  _Pragma("unroll") for (int ni = 0; ni < 4; ++ni) \
    bfr[ni] = *(const bf16x8*)((BR) + ni*512); \
  __builtin_amdgcn_s_setprio(1); \
  _Pragma("unroll") for (int mi = 0; mi < 4; ++mi) \
  _Pragma("unroll") for (int ni = 0; ni < 4; ++ni) \
    acc[mi][ni] = __builtin_amdgcn_mfma_f32_16x16x32_bf16( \
        afr[mi], bfr[ni], acc[mi][ni], 0, 0, 0); \
  __builtin_amdgcn_s_setprio(0); \
} while (0)

  STG(0, 0); STG(1, 1); STG(2, 2);
  #pragma unroll 1
  for (int i = 0; i < K/128; ++i) {     // 8 iters x 4 K-tiles (BK=32)
    const int t = 4*i;
    // tile t+3 buffer was last read at tile t-1, two barriers ago -> safe
    STG(3, t + 3);  VMC(12);            // t's 4 loads done; 12 (3 tiles) in flight
    BAR();  CMP(aP0, bP0);  BAR();
    if (i + 1 < K/128) { STG(0, t + 4); VMC(12); } else VMC(8);
    BAR();  CMP(aP1, bP1);  BAR();
    if (i + 1 < K/128) { STG(1, t + 5); VMC(12); } else VMC(4);
    BAR();  CMP(aP2, bP2);  BAR();
    if (i + 1 < K/128) { STG(2, t + 6); VMC(12); } else VMC(0);
    BAR();  CMP(aP3, bP3);  BAR();
  }
#undef STG
#undef CMP

  // epilogue. D layout: col = lane&15, row = (lane>>4)*4 + j  [m89/m91]
  if (EPI == 0) {
    const int ncol = n0 + wn*64;            // wave spans exactly one (part, head)
    const int part = ncol >> 10;            // 0=Q 1=K 2=V
    const int hid  = (ncol & 1023) >> 6;
    unsigned short* dstQK = (part == 0) ? Qh : Kh;
    #pragma unroll
    for (int mi = 0; mi < 4; ++mi) {
      #pragma unroll
      for (int j = 0; j < 4; ++j) {
        int row = m0 + wm*64 + mi*16 + l4*4 + j;
        int bb = row >> 11, tt = row & 2047;
        if (part < 2) {
          size_t base = ((size_t)((bb*NH_ + hid) * T_ + tt)) * HD_;
          #pragma unroll
          for (int ni = 0; ni < 2; ++ni) {
            int d = ni*16 + l15;
            float a1 = acc[mi][ni][j]     + bias[ncol + d];
            float a2 = acc[mi][ni + 2][j] + bias[ncol + d + 32];
            float cv = cosT[tt*32 + d], sv = sinT[tt*32 + d];
            float o1 = a1*cv - a2*sv;
            float o2 = a2*cv + a1*sv;
            // Q: fold 1/sqrt(64) * log2(e) so attention works in exp2 domain
            if (part == 0) { o1 *= 0.18033688011112042f; o2 *= 0.18033688011112042f; }
            dstQK[base + d]      = f2bf(o1);
            dstQK[base + d + 32] = f2bf(o2);
          }
        } else {
          #pragma unroll
          for (int ni = 0; ni < 4; ++ni) {
            int d = ni*16 + l15;
            float av = acc[mi][ni][j] + bias[ncol + d];
            VhT[((size_t)((bb*NH_ + hid) * HD_ + d)) * T_ + tt] = f2bf(av);
          }
        }
      }
    }
  } else {
    #pragma unroll
    for (int mi = 0; mi < 4; ++mi)
      #pragma unroll
      for (int ni = 0; ni < 4; ++ni)
        #pragma unroll
        for (int j = 0; j < 4; ++j) {
          int row = m0 + wm*64 + mi*16 + l4*4 + j;
          int col = n0 + wn*64 + ni*16 + l15;
          outF[(size_t)row * N + col] = acc[mi][ni][j] + bias[col];
        }
  }
}

// ---------------- flash attention (causal), 32x32 MFMA, swapped QK^T ----------------
// (R8/R11-verified version.) Qh pre-scaled by 0.125*log2(e); softmax via exp2.
// 1D grid: bh = blk&63, qb = 15-(blk>>6). Lane l owns q-row (l&31).
__global__ __launch_bounds__(256, 3)
void k_attn(const unsigned short* __restrict__ Qh,
            const unsigned short* __restrict__ Kh,
            const unsigned short* __restrict__ VhT,
            unsigned short* __restrict__ Y) {
  __shared__ alignas(16) unsigned short Ks[2][64*64];   // [key][d], XOR-swizzled 16B granules
  __shared__ alignas(16) unsigned short Vs[2][64*64];   // [d][key], XOR-swizzled
  const int tid  = threadIdx.x;
  const int lane = tid & 63;
  const int wv   = tid >> 6;
  const int l31  = lane & 31;
  const int h    = lane >> 5;
  const int bh   = blockIdx.x & 63;
  const int qb   = 15 - (blockIdx.x >> 6);          // balanced qb spread per CU
  const int r32  = qb*128 + wv*32;                  // wave's first q-row
  const int nt   = 2*qb + 2;
  const int qg   = r32 + l31;                       // this lane's q-row (global)

  // Q B-frags: qf[i] = Q[qg][d = i*16 + h*8 + e]
  bf16x8 qf[4];
  #pragma unroll
  for (int i = 0; i < 4; ++i)
    qf[i] = *(const bf16x8*)(Qh + ((size_t)(bh*T_ + qg))*HD_ + i*16 + h*8);

  float m_r = -1e30f, l_r = 0.f;
  f32x16 o[2] = {};   // o[dblk][r]: O[q = qg][d = dblk*32 + (r&3)+8*(r>>2)+4*h]

  auto stage = [&](int buf, int jt) {
    #pragma unroll
    for (int it = 0; it < 2; ++it) {
      int idx = it*256 + wv*64 + lane;
      int row = idx >> 3, slot = idx & 7;
      int g   = slot ^ (row & 7);
      gload16(Kh  + ((size_t)(bh*T_ + jt*64 + row))*HD_ + g*8,
              (void*)(Ks[buf] + (it*256 + wv*64)*8));
      gload16(VhT + ((size_t)(bh*HD_ + row))*T_ + jt*64 + g*8,
              (void*)(Vs[buf] + (it*256 + wv*64)*8));
    }
  };

  stage(0, 0);
  int cur = 0;

  for (int jt = 0; jt < nt; ++jt) {
    if (jt + 1 < nt) {
      stage(cur ^ 1, jt + 1);
      VMC(4);
    } else {
      VMC(0);
    }
    BAR();

    if (jt*64 <= r32 + 31) {     // wave-uniform skip of fully-masked tiles
      // S^T tiles: s[kb][r] = S[key = jt*64+kb*32+(r&3)+8*(r>>2)+4*h][q = qg]
      f32x16 s[2] = {f32x16{0}, f32x16{0}};
      __builtin_amdgcn_s_setprio(1);
      #pragma unroll
      for (int kb = 0; kb < 2; ++kb)
        #pragma unroll
        for (int i = 0; i < 4; ++i) {
          int r = kb*32 + l31;
          int g = (2*i + h) ^ (r & 7);
          bf16x8 kf = *(const bf16x8*)(Ks[cur] + r*64 + g*8);
          s[kb] = __builtin_amdgcn_mfma_f32_32x32x16_bf16(kf, qf[i], s[kb], 0, 0, 0);
        }
      __builtin_amdgcn_s_setprio(0);

      // extract + causal mask (diagonal tiles only)
      float p[2][16];
      const bool diag = (jt + 1)*64 > r32;
      #pragma unroll
      for (int kb = 0; kb < 2; ++kb)
        #pragma unroll
        for (int r = 0; r < 16; ++r) {
          float v = s[kb][r];
          if (diag) {
            int key = jt*64 + kb*32 + (r & 3) + 8*(r >> 2) + 4*h;
            v = (key > qg) ? -1e30f : v;
          }
          p[kb][r] = v;
        }

      // row max: in-lane tree + one cross-half swap
      float mx[16];
      #pragma unroll
      for (int r = 0; r < 16; ++r) mx[r] = fmaxf(p[0][r], p[1][r]);
      #pragma unroll
      for (int st = 8; st > 0; st >>= 1)
        #pragma unroll
        for (int r = 0; r < 8; ++r)
          if (r < st) mx[r] = fmaxf(mx[r], mx[r + st]);
      float tm = fmaxf(mx[0], __shfl_xor(mx[0], 32));

      // defer-max (T13): only rescale when tile max outgrows running max by >8
      if (!__all(tm <= m_r + 8.0f)) {
        float mn = fmaxf(m_r, tm);
        float scale = exp2f(m_r - mn);
        m_r = mn;
        l_r *= scale;
        #pragma unroll
        for (int dblk = 0; dblk < 2; ++dblk)
          #pragma unroll
          for (int r = 0; r < 16; ++r)
            o[dblk][r] *= scale;
      }

      #pragma unroll
      for (int kb = 0; kb < 2; ++kb)
        #pragma unroll
        for (int r = 0; r < 16; ++r)
          p[kb][r] = exp2f(p[kb][r] - m_r);

      float sm[16];
      #pragma unroll
      for (int r = 0; r < 16; ++r) sm[r] = p[0][r] + p[1][r];
      #pragma unroll
      for (int st = 8; st > 0; st >>= 1)
        #pragma unroll
        for (int r = 0; r < 8; ++r)
          if (r < st) sm[r] += sm[r + st];
      l_r += sm[0] + __shfl_xor(sm[0], 32);

      // PV per key-block: P B-frags via cvt_pk + ONE swap per pair (pre-selected).
      #pragma unroll
      for (int kb = 0; kb < 2; ++kb) {
        uint32_t a01 = cvtpk(p[kb][0],  p[kb][1]);
        uint32_t a23 = cvtpk(p[kb][2],  p[kb][3]);
        uint32_t a45 = cvtpk(p[kb][4],  p[kb][5]);
        uint32_t a67 = cvtpk(p[kb][6],  p[kb][7]);
        uint32_t b01 = cvtpk(p[kb][8],  p[kb][9]);
        uint32_t b23 = cvtpk(p[kb][10], p[kb][11]);
        uint32_t b45 = cvtpk(p[kb][12], p[kb][13]);
        uint32_t b67 = cvtpk(p[kb][14], p[kb][15]);
        uint32_t s1 = h ? a01 : a45, s2 = h ? a23 : a67;   // send what partner needs
        uint32_t s3 = h ? b01 : b45, s4 = h ? b23 : b67;
        uint32_t x1 = __shfl_xor(s1, 32), x2 = __shfl_xor(s2, 32);
        uint32_t x3 = __shfl_xor(s3, 32), x4 = __shfl_xor(s4, 32);
        union { bf16x8 v; uint32_t d[4]; } f0, f1;
        f0.d[0] = h ? x1 : a01;  f0.d[1] = h ? x2 : a23;
        f0.d[2] = h ? a45 : x1;  f0.d[3] = h ? a67 : x2;
        f1.d[0] = h ? x3 : b01;  f1.d[1] = h ? x4 : b23;
        f1.d[2] = h ? b45 : x3;  f1.d[3] = h ? b67 : x4;

        __builtin_amdgcn_s_setprio(1);
        #pragma unroll
        for (int koff = 0; koff < 2; ++koff) {
          bf16x8 pf = koff ? f1.v : f0.v;
          #pragma unroll
          for (int dblk = 0; dblk < 2; ++dblk) {
            int rv = dblk*32 + l31;
            int gv = (kb*4 + koff*2 + h) ^ (rv & 7);
            bf16x8 vf = *(const bf16x8*)(Vs[cur] + rv*64 + gv*8);
            // A = V^T (row=d, lane-local l31), B = P (col=q, lane-local l31)
            o[dblk] = __builtin_amdgcn_mfma_f32_32x32x16_bf16(vf, pf, o[dblk], 0, 0, 0);
          }
        }
        __builtin_amdgcn_s_setprio(0);
      }
    }

    BAR();   // raw: all LDS reads of this tile were consumed above
    cur ^= 1;
  }

  // epilogue: lane-local normalize, packed ushort4 stores
  int b = bh >> 4, hd = bh & 15;
  float rinv = 1.0f / l_r;
  unsigned short* yrow = Y + ((size_t)(b*T_ + r32 + l31))*C_ + hd*64;
  #pragma unroll
  for (int dblk = 0; dblk < 2; ++dblk)
    #pragma unroll
    for (int g2 = 0; g2 < 4; ++g2) {
      ushort4 o4;
      o4.x = f2bf(o[dblk][g2*4 + 0] * rinv);
      o4.y = f2bf(o[dblk][g2*4 + 1] * rinv);
      o4.z = f2bf(o[dblk][g2*4 + 2] * rinv);
      o4.w = f2bf(o[dblk][g2*4 + 3] * rinv);
      *(ushort4*)(yrow + dblk*32 + g2*8 + 4*h) = o4;
    }
}

// ---------------- host ----------------

extern "C" void kernel_launch(void* const* d_in, const int* in_sizes, int n_in,
                              void* d_out, int out_size, void* d_ws, size_t ws_size,
                              hipStream_t stream) {
  const float* x      = (const float*)d_in[0];
  const float* W_qkv  = (const float*)d_in[1];
  const float* b_qkv  = (const float*)d_in[2];
  const float* W_proj = (const float*)d_in[3];
  const float* b_proj = (const float*)d_in[4];
  float* out = (float*)d_out;

  char* ws = (char*)d_ws;
  size_t off = 0;
  auto alloc = [&](size_t bytes) {
    void* p = ws + off; off += (bytes + 255) & ~(size_t)255; return p;
  };
  unsigned short* xb     = (unsigned short*)alloc((size_t)M_ * C_ * 2);  // also reused as Y
  unsigned short* WqkvT  = (unsigned short*)alloc((size_t)3 * C_ * C_ * 2);
  unsigned short* WprojT = (unsigned short*)alloc((size_t)C_ * C_ * 2);
  unsigned short* Qh     = (unsigned short*)alloc((size_t)M_ * C_ * 2);
  unsigned short* Kh     = (unsigned short*)alloc((size_t)M_ * C_ * 2);
  unsigned short* VhT    = (unsigned short*)alloc((size_t)M_ * C_ * 2);
  float* cosT = (float*)alloc((size_t)T_ * 32 * 4);
  float* sinT = (float*)alloc((size_t)T_ * 32 * 4);
  unsigned short* Y = xb;   // xb dead after QKV GEMM; attention output aliases it

  k_cvt_bf16<<<(M_*C_/4 + 255)/256, 256, 0, stream>>>(x, xb, M_*C_);
  dim3 tb(32, 8);
  k_transpose_w<<<dim3(3*C_/32, C_/32), tb, 0, stream>>>(W_qkv, WqkvT, C_, 3*C_);
  k_transpose_w<<<dim3(C_/32,   C_/32), tb, 0, stream>>>(W_proj, WprojT, C_, C_);
  k_rope_tab<<<T_/8, tb, 0, stream>>>(cosT, sinT);

  // QKV: 64 m-tiles x 24 n-tiles = 1536 blocks = 3 exact residency rounds @2/CU
  k_gemm<3*C_, C_, 0><<<dim3(1536), 256, 0, stream>>>(
      xb, WqkvT, b_qkv, cosT, sinT, Qh, Kh, VhT, nullptr);

  // attn: QBLK=128, 4 waves/block; 16 qb x 64 bh = 1024 blocks
  k_attn<<<dim3(T_/128 * BH_), 256, 0, stream>>>(Qh, Kh, VhT, Y);

  // proj: 64 x 8 = 512 blocks, all co-resident @2/CU
  k_gemm<C_, C_, 1><<<dim3(512), 256, 0, stream>>>(
      Y, WprojT, b_proj, nullptr, nullptr, nullptr, nullptr, nullptr, out);
}

// Round 14
// 215.332 us; speedup vs baseline: 1.0267x; 1.0267x over previous
//
#include <hip/hip_runtime.h>
#include <stdint.h>

#define B_  4
#define T_  2048
#define C_  1024
#define NH_ 16
#define HD_ 64
#define BH_ (B_*NH_)   // 64
#define M_  (B_*T_)    // 8192

using f32x4  = __attribute__((ext_vector_type(4))) float;
using f32x16 = __attribute__((ext_vector_type(16))) float;
using bf16x8 = __attribute__((ext_vector_type(8))) short;   // 8 bf16 in 4 VGPRs

__device__ __forceinline__ unsigned short f2bf(float x) {
  union { float f; uint32_t u; } v; v.f = x;
  uint32_t u = v.u;
  return (unsigned short)((u + 0x7FFFu + ((u >> 16) & 1u)) >> 16);  // RNE
}

__device__ __forceinline__ uint32_t cvtpk(float a, float b) {
  uint32_t r;
  asm("v_cvt_pk_bf16_f32 %0, %1, %2" : "=v"(r) : "v"(a), "v"(b));
  return r;
}

// async global->LDS, 16B per lane. lds ptr must be wave-uniform base; HW adds lane*16.
__device__ __forceinline__ void gload16(const void* g, void* l) {
  __builtin_amdgcn_global_load_lds(
      (const __attribute__((address_space(1))) void*)g,
      (__attribute__((address_space(3))) void*)l, 16, 0, 0);
}

#define BAR() do { asm volatile("" ::: "memory"); __builtin_amdgcn_s_barrier(); \
                   asm volatile("" ::: "memory"); } while (0)
#define VMC(N) asm volatile("s_waitcnt vmcnt(" #N ")" ::: "memory")

// ---------------- prep kernels ----------------

__global__ void k_cvt_bf16(const float* __restrict__ src,
                           unsigned short* __restrict__ dst, int n) {
  int i = (blockIdx.x * 256 + threadIdx.x) * 4;
  if (i + 3 < n) {
    float4 v = *(const float4*)(src + i);
    ushort4 o;
    o.x = f2bf(v.x); o.y = f2bf(v.y); o.z = f2bf(v.z); o.w = f2bf(v.w);
    *(ushort4*)(dst + i) = o;
  }
}

// W [K][N] f32 -> WT [N][K] bf16, 32x32 LDS tile
__global__ void k_transpose_w(const float* __restrict__ W,
                              unsigned short* __restrict__ WT, int K, int N) {
  __shared__ float tile[32][33];
  int bx = blockIdx.x, by = blockIdx.y;
  int tx = threadIdx.x, ty = threadIdx.y;   // (32,8)
  #pragma unroll
  for (int i = 0; i < 32; i += 8)
    tile[ty + i][tx] = W[(size_t)(by*32 + ty + i) * N + bx*32 + tx];
  __syncthreads();
  #pragma unroll
  for (int i = 0; i < 32; i += 8)
    WT[(size_t)(bx*32 + ty + i) * K + by*32 + tx] = f2bf(tile[tx][ty + i]);
}

__global__ void k_rope_tab(float* __restrict__ cosT, float* __restrict__ sinT) {
  int t = blockIdx.x * 8 + threadIdx.y;   // block (32,8)
  int i = threadIdx.x;                    // 0..31
  float inv = expf(-(float)i * (9.210340371976184f / 32.0f));
  float f = (float)t * inv;
  cosT[t*32 + i] = cosf(f);
  sinT[t*32 + i] = sinf(f);
}

// ---- GEMM (R8-verified best): 128x128, BK=64, 4 waves, dbuf + vmcnt(8), hoisted ----
// A: [M][K] bf16 row-major. BT: [N][K] bf16 (B^T, K-contiguous).
template<int N, int K, int EPI>
__global__ __launch_bounds__(256)
void k_gemm(const unsigned short* __restrict__ Ag,
            const unsigned short* __restrict__ BT,
            const float* __restrict__ bias,
            const float* __restrict__ cosT,
            const float* __restrict__ sinT,
            unsigned short* __restrict__ Qh,
            unsigned short* __restrict__ Kh,
            unsigned short* __restrict__ VhT,
            float* __restrict__ outF) {
  __shared__ alignas(16) unsigned short As[2][128*64];
  __shared__ alignas(16) unsigned short Bs[2][128*64];
  const int tid  = threadIdx.x;
  const int lane = tid & 63;
  const int wv   = tid >> 6;
  const int wm   = wv >> 1, wn = wv & 1;
  const int l15  = lane & 15, l4 = lane >> 4;
  // XCD-aware bijective swizzle (grid % 8 == 0), n-fastest within chunk.
  const int NT  = N / 128;
  const int id  = ((int)blockIdx.x & 7) * ((int)gridDim.x >> 3) + ((int)blockIdx.x >> 3);
  const int m0  = (id / NT) * 128;
  const int n0  = (id % NT) * 128;

  f32x4 acc[4][4] = {};

  // ---- hoisted LDS read pointers (K-loop invariant; row&7 == l15&7) ----
  const int g0 = l4 ^ (l15 & 7);          // ks=0 granule
  const int g1 = (4 + l4) ^ (l15 & 7);    // ks=1 granule
  const int rowA = wm*64 + l15, rowB = wn*64 + l15;
  const unsigned short* aRd0k0 = &As[0][rowA*64 + g0*8];
  const unsigned short* aRd0k1 = &As[0][rowA*64 + g1*8];
  const unsigned short* aRd1k0 = &As[1][rowA*64 + g0*8];
  const unsigned short* aRd1k1 = &As[1][rowA*64 + g1*8];
  const unsigned short* bRd0k0 = &Bs[0][rowB*64 + g0*8];
  const unsigned short* bRd0k1 = &Bs[0][rowB*64 + g1*8];
  const unsigned short* bRd1k0 = &Bs[1][rowB*64 + g0*8];
  const unsigned short* bRd1k1 = &Bs[1][rowB*64 + g1*8];

  // ---- hoisted staging offsets ----
  const int srow = wv*8 + (lane >> 3);                 // row within 32-row unit
  const int sg   = (lane & 7) ^ ((lane >> 3) & 7);     // granule (it/wv-invariant)
  const int voff = srow*K + sg*8;                      // per-lane, A and B identical
  const int aUni = m0*K, bUni = n0*K;
  const int ldsD = wv*512;                             // wave's LDS dest (elements)

#define STG(BUF, KT) do { \
  const int _u = (KT)*64; \
  _Pragma("unroll") for (int it = 0; it < 4; ++it) { \
    gload16(Ag + (aUni + it*(32*K) + _u) + voff, (void*)(&As[BUF][it*2048 + ldsD])); \
    gload16(BT + (bUni + it*(32*K) + _u) + voff, (void*)(&Bs[BUF][it*2048 + ldsD])); \
  } \
} while (0)

#define CMP(AK0, AK1, BK0, BK1) do { \
  bf16x8 afr[4][2], bfr[4][2]; \
  _Pragma("unroll") for (int mi = 0; mi < 4; ++mi) { \
    afr[mi][0] = *(const bf16x8*)((AK0) + mi*1024); \
    afr[mi][1] = *(const bf16x8*)((AK1) + mi*1024); \
    bfr[mi][0] = *(const bf16x8*)((BK0) + mi*1024); \
    bfr[mi][1] = *(const bf16x8*)((BK1) + mi*1024); \
  } \
  __builtin_amdgcn_s_setprio(1); \
  _Pragma("unroll") for (int ks = 0; ks < 2; ++ks) \
  _Pragma("unroll") for (int mi = 0; mi < 4; ++mi) \
  _Pragma("unroll") for (int ni = 0; ni < 4; ++ni) \
    acc[mi][ni] = __builtin_amdgcn_mfma_f32_16x16x32_bf16( \
        afr[mi][ks], bfr[ni][ks], acc[mi][ni], 0, 0, 0); \
  __builtin_amdgcn_s_setprio(0); \
} while (0)

  STG(0, 0);
  #pragma unroll 1
  for (int i = 0; i < K/128; ++i) {
    STG(1, 2*i + 1);            // prefetch odd tile into buf1
    VMC(8);                     // buf0's 8 loads done; prefetch in flight
    BAR();
    CMP(aRd0k0, aRd0k1, bRd0k0, bRd0k1);
    BAR();
    if (i + 1 < K/128) {
      STG(0, 2*i + 2);          // prefetch next even tile into buf0
      VMC(8);
    } else {
      VMC(0);
    }
    BAR();
    CMP(aRd1k0, aRd1k1, bRd1k0, bRd1k1);
    BAR();
  }
#undef STG
#undef CMP

  // epilogue. D layout: col = lane&15, row = (lane>>4)*4 + j  [m89/m91]
  if (EPI == 0) {
    const int ncol = n0 + wn*64;            // wave spans exactly one (part, head)
    const int part = ncol >> 10;            // 0=Q 1=K 2=V
    const int hid  = (ncol & 1023) >> 6;
    unsigned short* dstQK = (part == 0) ? Qh : Kh;
    #pragma unroll
    for (int mi = 0; mi < 4; ++mi) {
      #pragma unroll
      for (int j = 0; j < 4; ++j) {
        int row = m0 + wm*64 + mi*16 + l4*4 + j;
        int bb = row >> 11, tt = row & 2047;
        if (part < 2) {
          size_t base = ((size_t)((bb*NH_ + hid) * T_ + tt)) * HD_;
          #pragma unroll
          for (int ni = 0; ni < 2; ++ni) {
            int d = ni*16 + l15;
            float a1 = acc[mi][ni][j]     + bias[ncol + d];
            float a2 = acc[mi][ni + 2][j] + bias[ncol + d + 32];
            float cv = cosT[tt*32 + d], sv = sinT[tt*32 + d];
            float o1 = a1*cv - a2*sv;
            float o2 = a2*cv + a1*sv;
            // Q: fold 1/sqrt(64) * log2(e) so attention works in exp2 domain
            if (part == 0) { o1 *= 0.18033688011112042f; o2 *= 0.18033688011112042f; }
            dstQK[base + d]      = f2bf(o1);
            dstQK[base + d + 32] = f2bf(o2);
          }
        } else {
          #pragma unroll
          for (int ni = 0; ni < 4; ++ni) {
            int d = ni*16 + l15;
            float av = acc[mi][ni][j] + bias[ncol + d];
            VhT[((size_t)((bb*NH_ + hid) * HD_ + d)) * T_ + tt] = f2bf(av);
          }
        }
      }
    }
  } else {
    #pragma unroll
    for (int mi = 0; mi < 4; ++mi)
      #pragma unroll
      for (int ni = 0; ni < 4; ++ni)
        #pragma unroll
        for (int j = 0; j < 4; ++j) {
          int row = m0 + wm*64 + mi*16 + l4*4 + j;
          int col = n0 + wn*64 + ni*16 + l15;
          outF[(size_t)row * N + col] = acc[mi][ni][j] + bias[col];
        }
  }
}

// ---------------- flash attention (causal), 32x32 MFMA, swapped QK^T ----------------
// R10 structure (correctness-verified), launch_bounds FIXED: no min-occupancy arg.
// 8 waves/block, QBLK=256: K/V tile shared by 8 waves (half the staging of 4-wave).
// Qh pre-scaled by 0.125*log2(e); softmax via exp2. 1D grid: bh=blk&63, qb=7-(blk>>6).
// Lane l owns q-row (l&31); S^T via mfma(K,Q); PV via mfma(V^T,P) => q lane-local.
__global__ __launch_bounds__(512)
void k_attn(const unsigned short* __restrict__ Qh,
            const unsigned short* __restrict__ Kh,
            const unsigned short* __restrict__ VhT,
            unsigned short* __restrict__ Y) {
  __shared__ alignas(16) unsigned short Ks[2][64*64];   // [key][d], XOR-swizzled 16B granules
  __shared__ alignas(16) unsigned short Vs[2][64*64];   // [d][key], XOR-swizzled
  const int tid  = threadIdx.x;
  const int lane = tid & 63;
  const int wv   = tid >> 6;                        // 0..7
  const int l31  = lane & 31;
  const int h    = lane >> 5;
  const int bh   = blockIdx.x & 63;
  const int qb   = 7 - (blockIdx.x >> 6);           // balanced qb spread per CU
  const int r32  = qb*256 + wv*32;                  // wave's first q-row
  const int nt   = 4*qb + 4;
  const int qg   = r32 + l31;                       // this lane's q-row (global)

  // Q B-frags: qf[i] = Q[qg][d = i*16 + h*8 + e]
  bf16x8 qf[4];
  #pragma unroll
  for (int i = 0; i < 4; ++i)
    qf[i] = *(const bf16x8*)(Qh + ((size_t)(bh*T_ + qg))*HD_ + i*16 + h*8);

  float m_r = -1e30f, l_r = 0.f;
  f32x16 o[2] = {};   // o[dblk][r]: O[q = qg][d = dblk*32 + (r&3)+8*(r>>2)+4*h]

  // stage: 512 threads cover the 512 granules of each tile (1 K + 1 V per lane)
  auto stage = [&](int buf, int jt) {
    int row = tid >> 3, slot = tid & 7;
    int g   = slot ^ (row & 7);
    gload16(Kh  + ((size_t)(bh*T_ + jt*64 + row))*HD_ + g*8,
            (void*)(Ks[buf] + wv*512));
    gload16(VhT + ((size_t)(bh*HD_ + row))*T_ + jt*64 + g*8,
            (void*)(Vs[buf] + wv*512));
  };

  stage(0, 0);
  int cur = 0;

  for (int jt = 0; jt < nt; ++jt) {
    if (jt + 1 < nt) {
      stage(cur ^ 1, jt + 1);
      VMC(2);                   // cur's 2 loads/lane done; prefetch in flight
    } else {
      VMC(0);
    }
    BAR();

    if (jt*64 <= r32 + 31) {     // wave-uniform skip of fully-masked tiles
      // S^T tiles: s[kb][r] = S[key = jt*64+kb*32+(r&3)+8*(r>>2)+4*h][q = qg]
      f32x16 s[2] = {f32x16{0}, f32x16{0}};
      __builtin_amdgcn_s_setprio(1);
      #pragma unroll
      for (int kb = 0; kb < 2; ++kb)
        #pragma unroll
        for (int i = 0; i < 4; ++i) {
          int r = kb*32 + l31;
          int g = (2*i + h) ^ (r & 7);
          bf16x8 kf = *(const bf16x8*)(Ks[cur] + r*64 + g*8);
          s[kb] = __builtin_amdgcn_mfma_f32_32x32x16_bf16(kf, qf[i], s[kb], 0, 0, 0);
        }
      __builtin_amdgcn_s_setprio(0);

      // extract + causal mask (diagonal tiles only)
      float p[2][16];
      const bool diag = (jt + 1)*64 > r32;
      #pragma unroll
      for (int kb = 0; kb < 2; ++kb)
        #pragma unroll
        for (int r = 0; r < 16; ++r) {
          float v = s[kb][r];
          if (diag) {
            int key = jt*64 + kb*32 + (r & 3) + 8*(r >> 2) + 4*h;
            v = (key > qg) ? -1e30f : v;
          }
          p[kb][r] = v;
        }

      // row max: in-lane tree + one cross-half swap
      float mx[16];
      #pragma unroll
      for (int r = 0; r < 16; ++r) mx[r] = fmaxf(p[0][r], p[1][r]);
      #pragma unroll
      for (int st = 8; st > 0; st >>= 1)
        #pragma unroll
        for (int r = 0; r < 8; ++r)
          if (r < st) mx[r] = fmaxf(mx[r], mx[r + st]);
      float tm = fmaxf(mx[0], __shfl_xor(mx[0], 32));

      // defer-max (T13): only rescale when tile max outgrows running max by >8
      if (!__all(tm <= m_r + 8.0f)) {
        float mn = fmaxf(m_r, tm);
        float scale = exp2f(m_r - mn);
        m_r = mn;
        l_r *= scale;
        #pragma unroll
        for (int dblk = 0; dblk < 2; ++dblk)
          #pragma unroll
          for (int r = 0; r < 16; ++r)
            o[dblk][r] *= scale;
      }

      #pragma unroll
      for (int kb = 0; kb < 2; ++kb)
        #pragma unroll
        for (int r = 0; r < 16; ++r)
          p[kb][r] = exp2f(p[kb][r] - m_r);

      float sm[16];
      #pragma unroll
      for (int r = 0; r < 16; ++r) sm[r] = p[0][r] + p[1][r];
      #pragma unroll
      for (int st = 8; st > 0; st >>= 1)
        #pragma unroll
        for (int r = 0; r < 8; ++r)
          if (r < st) sm[r] += sm[r + st];
      l_r += sm[0] + __shfl_xor(sm[0], 32);

      // PV per key-block: P B-frags via cvt_pk + ONE swap per pair (pre-selected).
      #pragma unroll
      for (int kb = 0; kb < 2; ++kb) {
        uint32_t a01 = cvtpk(p[kb][0],  p[kb][1]);
        uint32_t a23 = cvtpk(p[kb][2],  p[kb][3]);
        uint32_t a45 = cvtpk(p[kb][4],  p[kb][5]);
        uint32_t a67 = cvtpk(p[kb][6],  p[kb][7]);
        uint32_t b01 = cvtpk(p[kb][8],  p[kb][9]);
        uint32_t b23 = cvtpk(p[kb][10], p[kb][11]);
        uint32_t b45 = cvtpk(p[kb][12], p[kb][13]);
        uint32_t b67 = cvtpk(p[kb][14], p[kb][15]);
        uint32_t s1 = h ? a01 : a45, s2 = h ? a23 : a67;   // send what partner needs
        uint32_t s3 = h ? b01 : b45, s4 = h ? b23 : b67;
        uint32_t x1 = __shfl_xor(s1, 32), x2 = __shfl_xor(s2, 32);
        uint32_t x3 = __shfl_xor(s3, 32), x4 = __shfl_xor(s4, 32);
        union { bf16x8 v; uint32_t d[4]; } f0, f1;
        f0.d[0] = h ? x1 : a01;  f0.d[1] = h ? x2 : a23;
        f0.d[2] = h ? a45 : x1;  f0.d[3] = h ? a67 : x2;
        f1.d[0] = h ? x3 : b01;  f1.d[1] = h ? x4 : b23;
        f1.d[2] = h ? b45 : x3;  f1.d[3] = h ? b67 : x4;

        __builtin_amdgcn_s_setprio(1);
        #pragma unroll
        for (int koff = 0; koff < 2; ++koff) {
          bf16x8 pf = koff ? f1.v : f0.v;
          #pragma unroll
          for (int dblk = 0; dblk < 2; ++dblk) {
            int rv = dblk*32 + l31;
            int gv = (kb*4 + koff*2 + h) ^ (rv & 7);
            bf16x8 vf = *(const bf16x8*)(Vs[cur] + rv*64 + gv*8);
            // A = V^T (row=d, lane-local l31), B = P (col=q, lane-local l31)
            o[dblk] = __builtin_amdgcn_mfma_f32_32x32x16_bf16(vf, pf, o[dblk], 0, 0, 0);
          }
        }
        __builtin_amdgcn_s_setprio(0);
      }
    }

    BAR();   // raw: all LDS reads of this tile were consumed above
    cur ^= 1;
  }

  // epilogue: lane-local normalize, packed ushort4 stores
  int b = bh >> 4, hd = bh & 15;
  float rinv = 1.0f / l_r;
  unsigned short* yrow = Y + ((size_t)(b*T_ + r32 + l31))*C_ + hd*64;
  #pragma unroll
  for (int dblk = 0; dblk < 2; ++dblk)
    #pragma unroll
    for (int g2 = 0; g2 < 4; ++g2) {
      ushort4 o4;
      o4.x = f2bf(o[dblk][g2*4 + 0] * rinv);
      o4.y = f2bf(o[dblk][g2*4 + 1] * rinv);
      o4.z = f2bf(o[dblk][g2*4 + 2] * rinv);
      o4.w = f2bf(o[dblk][g2*4 + 3] * rinv);
      *(ushort4*)(yrow + dblk*32 + g2*8 + 4*h) = o4;
    }
}

// ---------------- host ----------------

extern "C" void kernel_launch(void* const* d_in, const int* in_sizes, int n_in,
                              void* d_out, int out_size, void* d_ws, size_t ws_size,
                              hipStream_t stream) {
  const float* x      = (const float*)d_in[0];
  const float* W_qkv  = (const float*)d_in[1];
  const float* b_qkv  = (const float*)d_in[2];
  const float* W_proj = (const float*)d_in[3];
  const float* b_proj = (const float*)d_in[4];
  float* out = (float*)d_out;

  char* ws = (char*)d_ws;
  size_t off = 0;
  auto alloc = [&](size_t bytes) {
    void* p = ws + off; off += (bytes + 255) & ~(size_t)255; return p;
  };
  unsigned short* xb     = (unsigned short*)alloc((size_t)M_ * C_ * 2);  // also reused as Y
  unsigned short* WqkvT  = (unsigned short*)alloc((size_t)3 * C_ * C_ * 2);
  unsigned short* WprojT = (unsigned short*)alloc((size_t)C_ * C_ * 2);
  unsigned short* Qh     = (unsigned short*)alloc((size_t)M_ * C_ * 2);
  unsigned short* Kh     = (unsigned short*)alloc((size_t)M_ * C_ * 2);
  unsigned short* VhT    = (unsigned short*)alloc((size_t)M_ * C_ * 2);
  float* cosT = (float*)alloc((size_t)T_ * 32 * 4);
  float* sinT = (float*)alloc((size_t)T_ * 32 * 4);
  unsigned short* Y = xb;   // xb dead after QKV GEMM; attention output aliases it

  k_cvt_bf16<<<(M_*C_/4 + 255)/256, 256, 0, stream>>>(x, xb, M_*C_);
  dim3 tb(32, 8);
  k_transpose_w<<<dim3(3*C_/32, C_/32), tb, 0, stream>>>(W_qkv, WqkvT, C_, 3*C_);
  k_transpose_w<<<dim3(C_/32,   C_/32), tb, 0, stream>>>(W_proj, WprojT, C_, C_);
  k_rope_tab<<<T_/8, tb, 0, stream>>>(cosT, sinT);

  // QKV: 64 m-tiles x 24 n-tiles = 1536 blocks (1D, XCD-swizzled in-kernel)
  k_gemm<3*C_, C_, 0><<<dim3(1536), 256, 0, stream>>>(
      xb, WqkvT, b_qkv, cosT, sinT, Qh, Kh, VhT, nullptr);

  // attn: QBLK=256, 8 waves/block; 8 qb x 64 bh = 512 blocks
  k_attn<<<dim3((T_/256) * BH_), 512, 0, stream>>>(Qh, Kh, VhT, Y);

  // proj: 64 x 8 = 512 blocks
  k_gemm<C_, C_, 1><<<dim3(512), 256, 0, stream>>>(
      Y, WprojT, b_proj, nullptr, nullptr, nullptr, nullptr, nullptr, out);
}

// Round 15
// 194.497 us; speedup vs baseline: 1.1367x; 1.1071x over previous
//
#include <hip/hip_runtime.h>
#include <stdint.h>

#define B_  4
#define T_  2048
#define C_  1024
#define NH_ 16
#define HD_ 64
#define BH_ (B_*NH_)   // 64
#define M_  (B_*T_)    // 8192

using f32x4  = __attribute__((ext_vector_type(4))) float;
using f32x16 = __attribute__((ext_vector_type(16))) float;
using bf16x8 = __attribute__((ext_vector_type(8))) short;   // 8 bf16 in 4 VGPRs

__device__ __forceinline__ unsigned short f2bf(float x) {
  union { float f; uint32_t u; } v; v.f = x;
  uint32_t u = v.u;
  return (unsigned short)((u + 0x7FFFu + ((u >> 16) & 1u)) >> 16);  // RNE
}

__device__ __forceinline__ uint32_t cvtpk(float a, float b) {
  uint32_t r;
  asm("v_cvt_pk_bf16_f32 %0, %1, %2" : "=v"(r) : "v"(a), "v"(b));
  return r;
}

// async global->LDS, 16B per lane. lds ptr must be wave-uniform base; HW adds lane*16.
__device__ __forceinline__ void gload16(const void* g, void* l) {
  __builtin_amdgcn_global_load_lds(
      (const __attribute__((address_space(1))) void*)g,
      (__attribute__((address_space(3))) void*)l, 16, 0, 0);
}

#define BAR() do { asm volatile("" ::: "memory"); __builtin_amdgcn_s_barrier(); \
                   asm volatile("" ::: "memory"); } while (0)
#define VMC(N) asm volatile("s_waitcnt vmcnt(" #N ")" ::: "memory")

// ---------------- fused prep: cvt + W transposes + rope tables, ONE launch --------
// Block ranges (all 256 threads):
//   [0, 8192)            : x f32 -> xb bf16 (1024 elems/block, float4)
//   [8192, 8192+3072)    : W_qkv [K][N] -> WqkvT [N][K] bf16 (32x32 tiles, 96 x 32)
//   [11264, 11264+1024)  : W_proj -> WprojT (32 x 32)
//   [12288, 12288+256)   : rope cos/sin tables (8 t-rows/block)
__global__ __launch_bounds__(256)
void k_prep(const float* __restrict__ x,      unsigned short* __restrict__ xb,
            const float* __restrict__ Wqkv,   unsigned short* __restrict__ WqkvT,
            const float* __restrict__ Wproj,  unsigned short* __restrict__ WprojT,
            float* __restrict__ cosT, float* __restrict__ sinT) {
  __shared__ float tile[32][33];
  const int blk = blockIdx.x;
  const int tid = threadIdx.x;
  if (blk < 8192) {                       // ---- cvt bf16
    int i = (blk * 256 + tid) * 4;
    float4 v = *(const float4*)(x + i);
    ushort4 o;
    o.x = f2bf(v.x); o.y = f2bf(v.y); o.z = f2bf(v.z); o.w = f2bf(v.w);
    *(ushort4*)(xb + i) = o;
    return;
  }
  const int tx = tid & 31, ty = tid >> 5; // (32,8) shape for the rest
  if (blk < 12288) {                      // ---- W transposes
    const float* W; unsigned short* WT; int N, local;
    if (blk < 11264) { W = Wqkv;  WT = WqkvT;  N = 3*C_; local = blk - 8192; }
    else             { W = Wproj; WT = WprojT; N = C_;   local = blk - 11264; }
    const int NT = N / 32;
    const int bx = local % NT, by = local / NT;
    #pragma unroll
    for (int i = 0; i < 32; i += 8)
      tile[ty + i][tx] = W[(size_t)(by*32 + ty + i) * N + bx*32 + tx];
    __syncthreads();
    #pragma unroll
    for (int i = 0; i < 32; i += 8)
      WT[(size_t)(bx*32 + ty + i) * C_ + by*32 + tx] = f2bf(tile[tx][ty + i]);
    return;
  }
  {                                       // ---- rope tables
    int t = (blk - 12288) * 8 + ty;
    float inv = expf(-(float)tx * (9.210340371976184f / 32.0f));
    float f = (float)t * inv;
    cosT[t*32 + tx] = cosf(f);
    sinT[t*32 + tx] = sinf(f);
  }
}

// ---- GEMM (R8-verified best): 128x128, BK=64, 4 waves, dbuf + vmcnt(8), hoisted ----
// A: [M][K] bf16 row-major. BT: [N][K] bf16 (B^T, K-contiguous).
template<int N, int K, int EPI>
__global__ __launch_bounds__(256)
void k_gemm(const unsigned short* __restrict__ Ag,
            const unsigned short* __restrict__ BT,
            const float* __restrict__ bias,
            const float* __restrict__ cosT,
            const float* __restrict__ sinT,
            unsigned short* __restrict__ Qh,
            unsigned short* __restrict__ Kh,
            unsigned short* __restrict__ VhT,
            float* __restrict__ outF) {
  __shared__ alignas(16) unsigned short As[2][128*64];
  __shared__ alignas(16) unsigned short Bs[2][128*64];
  const int tid  = threadIdx.x;
  const int lane = tid & 63;
  const int wv   = tid >> 6;
  const int wm   = wv >> 1, wn = wv & 1;
  const int l15  = lane & 15, l4 = lane >> 4;
  // XCD-aware bijective swizzle (grid % 8 == 0), n-fastest within chunk.
  const int NT  = N / 128;
  const int id  = ((int)blockIdx.x & 7) * ((int)gridDim.x >> 3) + ((int)blockIdx.x >> 3);
  const int m0  = (id / NT) * 128;
  const int n0  = (id % NT) * 128;

  f32x4 acc[4][4] = {};

  // ---- hoisted LDS read pointers (K-loop invariant; row&7 == l15&7) ----
  const int g0 = l4 ^ (l15 & 7);          // ks=0 granule
  const int g1 = (4 + l4) ^ (l15 & 7);    // ks=1 granule
  const int rowA = wm*64 + l15, rowB = wn*64 + l15;
  const unsigned short* aRd0k0 = &As[0][rowA*64 + g0*8];
  const unsigned short* aRd0k1 = &As[0][rowA*64 + g1*8];
  const unsigned short* aRd1k0 = &As[1][rowA*64 + g0*8];
  const unsigned short* aRd1k1 = &As[1][rowA*64 + g1*8];
  const unsigned short* bRd0k0 = &Bs[0][rowB*64 + g0*8];
  const unsigned short* bRd0k1 = &Bs[0][rowB*64 + g1*8];
  const unsigned short* bRd1k0 = &Bs[1][rowB*64 + g0*8];
  const unsigned short* bRd1k1 = &Bs[1][rowB*64 + g1*8];

  // ---- hoisted staging offsets ----
  const int srow = wv*8 + (lane >> 3);                 // row within 32-row unit
  const int sg   = (lane & 7) ^ ((lane >> 3) & 7);     // granule (it/wv-invariant)
  const int voff = srow*K + sg*8;                      // per-lane, A and B identical
  const int aUni = m0*K, bUni = n0*K;
  const int ldsD = wv*512;                             // wave's LDS dest (elements)

#define STG(BUF, KT) do { \
  const int _u = (KT)*64; \
  _Pragma("unroll") for (int it = 0; it < 4; ++it) { \
    gload16(Ag + (aUni + it*(32*K) + _u) + voff, (void*)(&As[BUF][it*2048 + ldsD])); \
    gload16(BT + (bUni + it*(32*K) + _u) + voff, (void*)(&Bs[BUF][it*2048 + ldsD])); \
  } \
} while (0)

#define CMP(AK0, AK1, BK0, BK1) do { \
  bf16x8 afr[4][2], bfr[4][2]; \
  _Pragma("unroll") for (int mi = 0; mi < 4; ++mi) { \
    afr[mi][0] = *(const bf16x8*)((AK0) + mi*1024); \
    afr[mi][1] = *(const bf16x8*)((AK1) + mi*1024); \
    bfr[mi][0] = *(const bf16x8*)((BK0) + mi*1024); \
    bfr[mi][1] = *(const bf16x8*)((BK1) + mi*1024); \
  } \
  __builtin_amdgcn_s_setprio(1); \
  _Pragma("unroll") for (int ks = 0; ks < 2; ++ks) \
  _Pragma("unroll") for (int mi = 0; mi < 4; ++mi) \
  _Pragma("unroll") for (int ni = 0; ni < 4; ++ni) \
    acc[mi][ni] = __builtin_amdgcn_mfma_f32_16x16x32_bf16( \
        afr[mi][ks], bfr[ni][ks], acc[mi][ni], 0, 0, 0); \
  __builtin_amdgcn_s_setprio(0); \
} while (0)

  STG(0, 0);
  #pragma unroll 1
  for (int i = 0; i < K/128; ++i) {
    STG(1, 2*i + 1);            // prefetch odd tile into buf1
    VMC(8);                     // buf0's 8 loads done; prefetch in flight
    BAR();
    CMP(aRd0k0, aRd0k1, bRd0k0, bRd0k1);
    BAR();
    if (i + 1 < K/128) {
      STG(0, 2*i + 2);          // prefetch next even tile into buf0
      VMC(8);
    } else {
      VMC(0);
    }
    BAR();
    CMP(aRd1k0, aRd1k1, bRd1k0, bRd1k1);
    BAR();
  }
#undef STG
#undef CMP

  // epilogue. D layout: col = lane&15, row = (lane>>4)*4 + j  [m89/m91]
  if (EPI == 0) {
    const int ncol = n0 + wn*64;            // wave spans exactly one (part, head)
    const int part = ncol >> 10;            // 0=Q 1=K 2=V
    const int hid  = (ncol & 1023) >> 6;
    unsigned short* dstQK = (part == 0) ? Qh : Kh;
    #pragma unroll
    for (int mi = 0; mi < 4; ++mi) {
      #pragma unroll
      for (int j = 0; j < 4; ++j) {
        int row = m0 + wm*64 + mi*16 + l4*4 + j;
        int bb = row >> 11, tt = row & 2047;
        if (part < 2) {
          size_t base = ((size_t)((bb*NH_ + hid) * T_ + tt)) * HD_;
          #pragma unroll
          for (int ni = 0; ni < 2; ++ni) {
            int d = ni*16 + l15;
            float a1 = acc[mi][ni][j]     + bias[ncol + d];
            float a2 = acc[mi][ni + 2][j] + bias[ncol + d + 32];
            float cv = cosT[tt*32 + d], sv = sinT[tt*32 + d];
            float o1 = a1*cv - a2*sv;
            float o2 = a2*cv + a1*sv;
            // Q: fold 1/sqrt(64) * log2(e) so attention works in exp2 domain
            if (part == 0) { o1 *= 0.18033688011112042f; o2 *= 0.18033688011112042f; }
            dstQK[base + d]      = f2bf(o1);
            dstQK[base + d + 32] = f2bf(o2);
          }
        } else {
          #pragma unroll
          for (int ni = 0; ni < 4; ++ni) {
            int d = ni*16 + l15;
            float av = acc[mi][ni][j] + bias[ncol + d];
            VhT[((size_t)((bb*NH_ + hid) * HD_ + d)) * T_ + tt] = f2bf(av);
          }
        }
      }
    }
  } else {
    #pragma unroll
    for (int mi = 0; mi < 4; ++mi)
      #pragma unroll
      for (int ni = 0; ni < 4; ++ni)
        #pragma unroll
        for (int j = 0; j < 4; ++j) {
          int row = m0 + wm*64 + mi*16 + l4*4 + j;
          int col = n0 + wn*64 + ni*16 + l15;
          outF[(size_t)row * N + col] = acc[mi][ni][j] + bias[col];
        }
  }
}

// ---------------- flash attention (causal), 32x32 MFMA, swapped QK^T ----------------
// (R8/R11-verified version — best measured.) Qh pre-scaled by 0.125*log2(e);
// softmax via exp2. 1D grid: bh = blk&63, qb = 15-(blk>>6). Lane l owns q-row (l&31).
__global__ __launch_bounds__(256, 3)
void k_attn(const unsigned short* __restrict__ Qh,
            const unsigned short* __restrict__ Kh,
            const unsigned short* __restrict__ VhT,
            unsigned short* __restrict__ Y) {
  __shared__ alignas(16) unsigned short Ks[2][64*64];   // [key][d], XOR-swizzled 16B granules
  __shared__ alignas(16) unsigned short Vs[2][64*64];   // [d][key], XOR-swizzled
  const int tid  = threadIdx.x;
  const int lane = tid & 63;
  const int wv   = tid >> 6;
  const int l31  = lane & 31;
  const int h    = lane >> 5;
  const int bh   = blockIdx.x & 63;
  const int qb   = 15 - (blockIdx.x >> 6);          // balanced qb spread per CU
  const int r32  = qb*128 + wv*32;                  // wave's first q-row
  const int nt   = 2*qb + 2;
  const int qg   = r32 + l31;                       // this lane's q-row (global)

  // Q B-frags: qf[i] = Q[qg][d = i*16 + h*8 + e]
  bf16x8 qf[4];
  #pragma unroll
  for (int i = 0; i < 4; ++i)
    qf[i] = *(const bf16x8*)(Qh + ((size_t)(bh*T_ + qg))*HD_ + i*16 + h*8);

  float m_r = -1e30f, l_r = 0.f;
  f32x16 o[2] = {};   // o[dblk][r]: O[q = qg][d = dblk*32 + (r&3)+8*(r>>2)+4*h]

  auto stage = [&](int buf, int jt) {
    #pragma unroll
    for (int it = 0; it < 2; ++it) {
      int idx = it*256 + wv*64 + lane;
      int row = idx >> 3, slot = idx & 7;
      int g   = slot ^ (row & 7);
      gload16(Kh  + ((size_t)(bh*T_ + jt*64 + row))*HD_ + g*8,
              (void*)(Ks[buf] + (it*256 + wv*64)*8));
      gload16(VhT + ((size_t)(bh*HD_ + row))*T_ + jt*64 + g*8,
              (void*)(Vs[buf] + (it*256 + wv*64)*8));
    }
  };

  stage(0, 0);
  int cur = 0;

  for (int jt = 0; jt < nt; ++jt) {
    if (jt + 1 < nt) {
      stage(cur ^ 1, jt + 1);
      VMC(4);
    } else {
      VMC(0);
    }
    BAR();

    if (jt*64 <= r32 + 31) {     // wave-uniform skip of fully-masked tiles
      // S^T tiles: s[kb][r] = S[key = jt*64+kb*32+(r&3)+8*(r>>2)+4*h][q = qg]
      f32x16 s[2] = {f32x16{0}, f32x16{0}};
      __builtin_amdgcn_s_setprio(1);
      #pragma unroll
      for (int kb = 0; kb < 2; ++kb)
        #pragma unroll
        for (int i = 0; i < 4; ++i) {
          int r = kb*32 + l31;
          int g = (2*i + h) ^ (r & 7);
          bf16x8 kf = *(const bf16x8*)(Ks[cur] + r*64 + g*8);
          s[kb] = __builtin_amdgcn_mfma_f32_32x32x16_bf16(kf, qf[i], s[kb], 0, 0, 0);
        }
      __builtin_amdgcn_s_setprio(0);

      // extract + causal mask (diagonal tiles only)
      float p[2][16];
      const bool diag = (jt + 1)*64 > r32;
      #pragma unroll
      for (int kb = 0; kb < 2; ++kb)
        #pragma unroll
        for (int r = 0; r < 16; ++r) {
          float v = s[kb][r];
          if (diag) {
            int key = jt*64 + kb*32 + (r & 3) + 8*(r >> 2) + 4*h;
            v = (key > qg) ? -1e30f : v;
          }
          p[kb][r] = v;
        }

      // row max: in-lane tree + one cross-half swap
      float mx[16];
      #pragma unroll
      for (int r = 0; r < 16; ++r) mx[r] = fmaxf(p[0][r], p[1][r]);
      #pragma unroll
      for (int st = 8; st > 0; st >>= 1)
        #pragma unroll
        for (int r = 0; r < 8; ++r)
          if (r < st) mx[r] = fmaxf(mx[r], mx[r + st]);
      float tm = fmaxf(mx[0], __shfl_xor(mx[0], 32));

      // defer-max (T13): only rescale when tile max outgrows running max by >8
      if (!__all(tm <= m_r + 8.0f)) {
        float mn = fmaxf(m_r, tm);
        float scale = exp2f(m_r - mn);
        m_r = mn;
        l_r *= scale;
        #pragma unroll
        for (int dblk = 0; dblk < 2; ++dblk)
          #pragma unroll
          for (int r = 0; r < 16; ++r)
            o[dblk][r] *= scale;
      }

      #pragma unroll
      for (int kb = 0; kb < 2; ++kb)
        #pragma unroll
        for (int r = 0; r < 16; ++r)
          p[kb][r] = exp2f(p[kb][r] - m_r);

      float sm[16];
      #pragma unroll
      for (int r = 0; r < 16; ++r) sm[r] = p[0][r] + p[1][r];
      #pragma unroll
      for (int st = 8; st > 0; st >>= 1)
        #pragma unroll
        for (int r = 0; r < 8; ++r)
          if (r < st) sm[r] += sm[r + st];
      l_r += sm[0] + __shfl_xor(sm[0], 32);

      // PV per key-block: P B-frags via cvt_pk + ONE swap per pair (pre-selected).
      #pragma unroll
      for (int kb = 0; kb < 2; ++kb) {
        uint32_t a01 = cvtpk(p[kb][0],  p[kb][1]);
        uint32_t a23 = cvtpk(p[kb][2],  p[kb][3]);
        uint32_t a45 = cvtpk(p[kb][4],  p[kb][5]);
        uint32_t a67 = cvtpk(p[kb][6],  p[kb][7]);
        uint32_t b01 = cvtpk(p[kb][8],  p[kb][9]);
        uint32_t b23 = cvtpk(p[kb][10], p[kb][11]);
        uint32_t b45 = cvtpk(p[kb][12], p[kb][13]);
        uint32_t b67 = cvtpk(p[kb][14], p[kb][15]);
        uint32_t s1 = h ? a01 : a45, s2 = h ? a23 : a67;   // send what partner needs
        uint32_t s3 = h ? b01 : b45, s4 = h ? b23 : b67;
        uint32_t x1 = __shfl_xor(s1, 32), x2 = __shfl_xor(s2, 32);
        uint32_t x3 = __shfl_xor(s3, 32), x4 = __shfl_xor(s4, 32);
        union { bf16x8 v; uint32_t d[4]; } f0, f1;
        f0.d[0] = h ? x1 : a01;  f0.d[1] = h ? x2 : a23;
        f0.d[2] = h ? a45 : x1;  f0.d[3] = h ? a67 : x2;
        f1.d[0] = h ? x3 : b01;  f1.d[1] = h ? x4 : b23;
        f1.d[2] = h ? b45 : x3;  f1.d[3] = h ? b67 : x4;

        __builtin_amdgcn_s_setprio(1);
        #pragma unroll
        for (int koff = 0; koff < 2; ++koff) {
          bf16x8 pf = koff ? f1.v : f0.v;
          #pragma unroll
          for (int dblk = 0; dblk < 2; ++dblk) {
            int rv = dblk*32 + l31;
            int gv = (kb*4 + koff*2 + h) ^ (rv & 7);
            bf16x8 vf = *(const bf16x8*)(Vs[cur] + rv*64 + gv*8);
            // A = V^T (row=d, lane-local l31), B = P (col=q, lane-local l31)
            o[dblk] = __builtin_amdgcn_mfma_f32_32x32x16_bf16(vf, pf, o[dblk], 0, 0, 0);
          }
        }
        __builtin_amdgcn_s_setprio(0);
      }
    }

    BAR();   // raw: all LDS reads of this tile were consumed above
    cur ^= 1;
  }

  // epilogue: lane-local normalize, packed ushort4 stores
  int b = bh >> 4, hd = bh & 15;
  float rinv = 1.0f / l_r;
  unsigned short* yrow = Y + ((size_t)(b*T_ + r32 + l31))*C_ + hd*64;
  #pragma unroll
  for (int dblk = 0; dblk < 2; ++dblk)
    #pragma unroll
    for (int g2 = 0; g2 < 4; ++g2) {
      ushort4 o4;
      o4.x = f2bf(o[dblk][g2*4 + 0] * rinv);
      o4.y = f2bf(o[dblk][g2*4 + 1] * rinv);
      o4.z = f2bf(o[dblk][g2*4 + 2] * rinv);
      o4.w = f2bf(o[dblk][g2*4 + 3] * rinv);
      *(ushort4*)(yrow + dblk*32 + g2*8 + 4*h) = o4;
    }
}

// ---------------- host ----------------

extern "C" void kernel_launch(void* const* d_in, const int* in_sizes, int n_in,
                              void* d_out, int out_size, void* d_ws, size_t ws_size,
                              hipStream_t stream) {
  const float* x      = (const float*)d_in[0];
  const float* W_qkv  = (const float*)d_in[1];
  const float* b_qkv  = (const float*)d_in[2];
  const float* W_proj = (const float*)d_in[3];
  const float* b_proj = (const float*)d_in[4];
  float* out = (float*)d_out;

  char* ws = (char*)d_ws;
  size_t off = 0;
  auto alloc = [&](size_t bytes) {
    void* p = ws + off; off += (bytes + 255) & ~(size_t)255; return p;
  };
  unsigned short* xb     = (unsigned short*)alloc((size_t)M_ * C_ * 2);  // also reused as Y
  unsigned short* WqkvT  = (unsigned short*)alloc((size_t)3 * C_ * C_ * 2);
  unsigned short* WprojT = (unsigned short*)alloc((size_t)C_ * C_ * 2);
  unsigned short* Qh     = (unsigned short*)alloc((size_t)M_ * C_ * 2);
  unsigned short* Kh     = (unsigned short*)alloc((size_t)M_ * C_ * 2);
  unsigned short* VhT    = (unsigned short*)alloc((size_t)M_ * C_ * 2);
  float* cosT = (float*)alloc((size_t)T_ * 32 * 4);
  float* sinT = (float*)alloc((size_t)T_ * 32 * 4);
  unsigned short* Y = xb;   // xb dead after QKV GEMM; attention output aliases it

  // fused prep: 8192 cvt + 3072 qkvT + 1024 projT + 256 rope = 12544 blocks
  k_prep<<<dim3(12544), 256, 0, stream>>>(x, xb, W_qkv, WqkvT, W_proj, WprojT,
                                          cosT, sinT);

  // QKV: 64 m-tiles x 24 n-tiles = 1536 blocks (1D, XCD-swizzled in-kernel)
  k_gemm<3*C_, C_, 0><<<dim3(1536), 256, 0, stream>>>(
      xb, WqkvT, b_qkv, cosT, sinT, Qh, Kh, VhT, nullptr);

  // attn: QBLK=128, 4 waves/block; 16 qb x 64 bh = 1024 blocks
  k_attn<<<dim3(T_/128 * BH_), 256, 0, stream>>>(Qh, Kh, VhT, Y);

  // proj: 64 x 8 = 512 blocks
  k_gemm<C_, C_, 1><<<dim3(512), 256, 0, stream>>>(
      Y, WprojT, b_proj, nullptr, nullptr, nullptr, nullptr, nullptr, out);
}